// Round 13
// baseline (1548.782 us; speedup 1.0000x reference)
//
#include <hip/hip_runtime.h>

#define NN 50000
#define NE 800000
#define DIN 32
#define DD 96
#define NL 4
#define NCLS 10
#define EPSF 1e-6f

typedef unsigned short u16;
typedef unsigned int u32;

typedef __bf16 bf16x8 __attribute__((ext_vector_type(8)));
typedef float f32x4 __attribute__((ext_vector_type(4)));

static __device__ __forceinline__ float bf2f(u16 u) {
    return __uint_as_float(((u32)u) << 16);
}
static __device__ __forceinline__ u16 f2bf(float f) {
    u32 x = __float_as_uint(f);
    x += 0x7FFFu + ((x >> 16) & 1u);   // round-to-nearest-even
    return (u16)(x >> 16);
}
static __device__ __forceinline__ u32 pk2(float a, float b) {
    return (u32)f2bf(a) | ((u32)f2bf(b) << 16);
}
static __device__ __forceinline__ float unlo(u32 u) { return __uint_as_float(u << 16); }
static __device__ __forceinline__ float unhi(u32 u) { return __uint_as_float(u & 0xFFFF0000u); }

__global__ void k_zero_i(int* __restrict__ p, int n) {
    int i = blockIdx.x * blockDim.x + threadIdx.x;
    if (i < n) p[i] = 0;
}

__global__ void k_zero_f4(float4* __restrict__ p, int n4) {
    int i = blockIdx.x * blockDim.x + threadIdx.x;
    if (i < n4) p[i] = make_float4(0.f, 0.f, 0.f, 0.f);
}

__global__ void k_hist(const int* __restrict__ dst, int* __restrict__ counts) {
    int i = blockIdx.x * blockDim.x + threadIdx.x;
    if (i < NE) atomicAdd(&counts[dst[i]], 1);
}

// single-block exclusive scan over n counts -> ptr[0..n], cursor copy.
__global__ __launch_bounds__(1024) void k_scan(const int* __restrict__ counts,
                                               int* __restrict__ ptr,
                                               int* __restrict__ cursor, int n) {
    __shared__ int wsum[16];
    __shared__ int carry_s;
    const int tid = threadIdx.x;
    const int lane = tid & 63, wid = tid >> 6;
    if (tid == 0) carry_s = 0;
    __syncthreads();
    for (int base = 0; base < n; base += 1024) {
        int i = base + tid;
        int v = (i < n) ? counts[i] : 0;
        int x = v;
#pragma unroll
        for (int off = 1; off < 64; off <<= 1) {
            int t = __shfl_up(x, (unsigned)off, 64);
            if (lane >= off) x += t;
        }
        if (lane == 63) wsum[wid] = x;
        __syncthreads();
        if (wid == 0 && lane < 16) {
            int s = wsum[lane];
#pragma unroll
            for (int off = 1; off < 16; off <<= 1) {
                int t = __shfl_up(s, (unsigned)off, 16);
                if (lane >= off) s += t;
            }
            wsum[lane] = s;
        }
        __syncthreads();
        int wbase = (wid > 0) ? wsum[wid - 1] : 0;
        int carry = carry_s;
        int excl = carry + wbase + x - v;
        if (i < n) { ptr[i] = excl; cursor[i] = excl; }
        __syncthreads();
        if (tid == 0) carry_s = carry + wsum[15];
        __syncthreads();
    }
    if (tid == 0) ptr[n] = carry_s;
}

__global__ void k_scatter(const int* __restrict__ src, const int* __restrict__ dst,
                          int* __restrict__ cursor, int* __restrict__ eperm,
                          int* __restrict__ srcp) {
    int i = blockIdx.x * blockDim.x + threadIdx.x;
    if (i >= NE) return;
    int pos = atomicAdd(&cursor[dst[i]], 1);
    eperm[pos] = i;
    srcp[pos] = src[i];
}

// counts[n] = ceil(deg/16)
__global__ void k_chunkcnt(const int* __restrict__ row_ptr, int* __restrict__ counts) {
    int n = blockIdx.x * blockDim.x + threadIdx.x;
    if (n < NN) counts[n] = (row_ptr[n + 1] - row_ptr[n] + 15) / 16;
}

// flat chunk list: (node, start edge) per 16-edge chunk
__global__ void k_fillchunk(const int* __restrict__ row_ptr, const int* __restrict__ chunk_ptr,
                            int* __restrict__ chunk_node, int* __restrict__ chunk_start) {
    int n = blockIdx.x * blockDim.x + threadIdx.x;
    if (n >= NN) return;
    int r0 = row_ptr[n], r1 = row_ptr[n + 1];
    int base = chunk_ptr[n];
    for (int c = 0; r0 + 16 * c < r1; ++c) {
        chunk_node[base + c] = n;
        chunk_start[base + c] = r0 + 16 * c;
    }
}

// Pack a [NL][96][96] weight tensor into MFMA B-fragment order (bf16).
// kperm!=0: k-axis permuted by pi(k)=(k%6)*16+k/6 (Cw: e-state stored-pi k).
__global__ void k_packCw(const float* __restrict__ W_all, u16* __restrict__ wf, int kperm) {
    int q = blockIdx.x * blockDim.x + threadIdx.x;
    if (q >= NL * 6 * 3 * 64) return;
    int l = q / (6 * 3 * 64);
    int rem = q - l * (6 * 3 * 64);
    int tile = rem / (3 * 64);
    int rem2 = rem - tile * (3 * 64);
    int c = rem2 >> 6, lane = rem2 & 63;
    const float* W = W_all + (long)l * DD * DD;
    int n = tile * 16 + (lane & 15);
    int k0 = c * 32 + (lane >> 4) * 8;
    u16 w[8];
#pragma unroll
    for (int j = 0; j < 8; ++j) {
        int kk = k0 + j;
        int kact = kperm ? ((kk % 6) * 16 + kk / 6) : kk;
        w[j] = f2bf(W[kact * DD + n]);
    }
    *(uint4*)&wf[(long)q * 8] = *(uint4*)w;
}

// Pack a [32,96] projection W into B-fragment order
__global__ void k_packW32(const float* __restrict__ W, u16* __restrict__ wf) {
    int q = blockIdx.x * blockDim.x + threadIdx.x;
    if (q >= 6 * 64) return;
    int tile = q >> 6, lane = q & 63;
    int n = tile * 16 + (lane & 15);
    int k0 = (lane >> 4) * 8;
    u16 w[8];
#pragma unroll
    for (int j = 0; j < 8; ++j) w[j] = f2bf(W[(k0 + j) * DD + n]);
    *(uint4*)&wf[q * 8] = *(uint4*)w;
}

// Barrier-free MFMA input projection: one wave per 16-row tile, grid-stride.
template <bool BFOUT, bool PERM, bool POUT>
__global__ __launch_bounds__(256) void k_proj_m(const float* __restrict__ X,
                                                const u16* __restrict__ wf,
                                                const float* __restrict__ B,
                                                void* __restrict__ Y,
                                                const int* __restrict__ eperm,
                                                int ntiles) {
    const int lane = threadIdx.x & 63;
    const int gw = (blockIdx.x * blockDim.x + threadIdx.x) >> 6;
    const int nw = (gridDim.x * blockDim.x) >> 6;
    const int lm = lane & 15, quad = lane >> 4;

    bf16x8 bfr[6];
    float bias[6];
#pragma unroll
    for (int t = 0; t < 6; ++t) {
        bfr[t] = *(const bf16x8*)&wf[(t * 64 + lane) * 8];
        bias[t] = B[t * 16 + lm];
    }

    for (int tile = gw; tile < ntiles; tile += nw) {
        const int row = tile * 16 + lm;
        const long srow = PERM ? (long)eperm[row] : (long)row;
        float4 x0 = *(const float4*)&X[srow * DIN + quad * 8];
        float4 x1 = *(const float4*)&X[srow * DIN + quad * 8 + 4];
        u32 ap[4] = {pk2(x0.x, x0.y), pk2(x0.z, x0.w), pk2(x1.x, x1.y), pk2(x1.z, x1.w)};
        bf16x8 af = *(bf16x8*)ap;
        f32x4 acc[6];
#pragma unroll
        for (int t = 0; t < 6; ++t) {
            acc[t] = (f32x4){0.f, 0.f, 0.f, 0.f};
            acc[t] = __builtin_amdgcn_mfma_f32_16x16x32_bf16(af, bfr[t], acc[t], 0, 0, 0);
        }
        const long rbase = (long)tile * 16 + quad * 4;
        if (POUT) {
#pragma unroll
            for (int r = 0; r < 4; ++r) {
                u16* p = (u16*)Y + (rbase + r) * DD + lm * 6;
                *(u32*)p       = pk2(acc[0][r] + bias[0], acc[1][r] + bias[1]);
                *(u32*)(p + 2) = pk2(acc[2][r] + bias[2], acc[3][r] + bias[3]);
                *(u32*)(p + 4) = pk2(acc[4][r] + bias[4], acc[5][r] + bias[5]);
            }
        } else {
#pragma unroll
            for (int t = 0; t < 6; ++t) {
                const int j = t * 16 + lm;
#pragma unroll
                for (int r = 0; r < 4; ++r) {
                    float v = acc[t][r] + bias[t];
                    if (BFOUT) ((u16*)Y)[(rbase + r) * DD + j] = f2bf(v);
                    else       ((float*)Y)[(rbase + r) * DD + j] = v;
                }
            }
        }
    }
}

// Barrier-free MFMA 4-way node GEMM: wave w of each block handles matrix w.
__global__ __launch_bounds__(256) void k_gemm4m(const float* __restrict__ X,
                                                const u16* __restrict__ awf, const float* __restrict__ ab,
                                                const u16* __restrict__ bwf, const float* __restrict__ bb,
                                                const u16* __restrict__ dwf, const float* __restrict__ db,
                                                const u16* __restrict__ ewf, const float* __restrict__ eb,
                                                float* __restrict__ Y0, u16* __restrict__ Y1,
                                                u16* __restrict__ Y2, u16* __restrict__ Y3,
                                                int ntiles) {
    const int lane = threadIdx.x & 63;
    const int w = threadIdx.x >> 6;   // matrix 0..3
    const int lm = lane & 15, quad = lane >> 4;
    const u16* wf = (w == 0) ? awf : (w == 1) ? bwf : (w == 2) ? dwf : ewf;
    const float* bp = (w == 0) ? ab : (w == 1) ? bb : (w == 2) ? db : eb;

    bf16x8 bfr[6][3];
    float bias[6];
#pragma unroll
    for (int t = 0; t < 6; ++t) {
#pragma unroll
        for (int c = 0; c < 3; ++c)
            bfr[t][c] = *(const bf16x8*)&wf[((t * 3 + c) * 64 + lane) * 8];
        bias[t] = bp[t * 16 + lm];
    }

    for (int tile = blockIdx.x; tile < ntiles; tile += gridDim.x) {
        const float* xr = X + (long)(tile * 16 + lm) * DD;
        bf16x8 a[3];
#pragma unroll
        for (int c = 0; c < 3; ++c) {
            float4 x0 = *(const float4*)&xr[c * 32 + quad * 8];
            float4 x1 = *(const float4*)&xr[c * 32 + quad * 8 + 4];
            u32 ap[4] = {pk2(x0.x, x0.y), pk2(x0.z, x0.w), pk2(x1.x, x1.y), pk2(x1.z, x1.w)};
            a[c] = *(bf16x8*)ap;
        }
        f32x4 acc[6];
#pragma unroll
        for (int t = 0; t < 6; ++t) {
            acc[t] = (f32x4){0.f, 0.f, 0.f, 0.f};
#pragma unroll
            for (int c = 0; c < 3; ++c)
                acc[t] = __builtin_amdgcn_mfma_f32_16x16x32_bf16(a[c], bfr[t][c], acc[t], 0, 0, 0);
        }
        const long rbase = (long)tile * 16 + quad * 4;
        if (w == 0) {
#pragma unroll
            for (int t = 0; t < 6; ++t) {
                const int j = t * 16 + lm;
#pragma unroll
                for (int r = 0; r < 4; ++r) Y0[(rbase + r) * DD + j] = acc[t][r] + bias[t];
            }
        } else {
            u16* Yp = (w == 1) ? Y1 : (w == 2) ? Y2 : Y3;
#pragma unroll
            for (int r = 0; r < 4; ++r) {
                u16* p = Yp + (rbase + r) * DD + lm * 6;
                *(u32*)p       = pk2(acc[0][r] + bias[0], acc[1][r] + bias[1]);
                *(u32*)(p + 2) = pk2(acc[2][r] + bias[2], acc[3][r] + bias[3]);
                *(u32*)(p + 4) = pk2(acc[4][r] + bias[4], acc[5][r] + bias[5]);
            }
        }
    }
}

// Phase A: one wave per 16-edge chunk (uniform work, grid-stride over flat
// chunk list). Computes e_new/sigma, updates e in place, quad-reduces partial
// num/den and atomically adds them (canonical basis, coalesced 64B segments).
__global__ __launch_bounds__(256) void k_edge_c(u16* ebuf,
                                                const u16* __restrict__ cwf,
                                                const float* __restrict__ Cb,
                                                const u16* __restrict__ Dh,
                                                const u16* __restrict__ Eh,
                                                const u16* __restrict__ Bh,
                                                const int* __restrict__ srcp,
                                                const int* __restrict__ row_ptr,
                                                const int* __restrict__ chunk_node,
                                                const int* __restrict__ chunk_start,
                                                const int* __restrict__ chunk_total,
                                                float* __restrict__ num,
                                                float* __restrict__ den) {
    const int lane = threadIdx.x & 63;
    const int gw = (blockIdx.x * blockDim.x + threadIdx.x) >> 6;
    const int nw = (gridDim.x * blockDim.x) >> 6;
    const int lm = lane & 15, quad = lane >> 4;

    bf16x8 bfrag[6][3];
    float cb[6];
#pragma unroll
    for (int t = 0; t < 6; ++t) {
#pragma unroll
        for (int c = 0; c < 3; ++c)
            bfrag[t][c] = *(const bf16x8*)&cwf[((t * 3 + c) * 64 + lane) * 8];
        cb[t] = Cb[t * 16 + lm];
    }
    const int cnt = *chunk_total;

    for (int ci = gw; ci < cnt; ci += nw) {
        const int n = chunk_node[ci];
        const int start = chunk_start[ci];
        const int rows = min(16, row_ptr[n + 1] - start);
        float eh[6];
        {
            const u16* ep = Eh + (long)n * DD + lm * 6;
            u32 e0 = *(const u32*)ep, e1 = *(const u32*)(ep + 2), e2 = *(const u32*)(ep + 4);
            eh[0] = unlo(e0); eh[1] = unhi(e0); eh[2] = unlo(e1);
            eh[3] = unhi(e1); eh[4] = unlo(e2); eh[5] = unhi(e2);
        }
        const long arow = start + (lm < rows ? lm : 0);
        bf16x8 a[3];
#pragma unroll
        for (int c = 0; c < 3; ++c)
            a[c] = *(const bf16x8*)&ebuf[arow * DD + c * 32 + quad * 8];
        int sr[4];
#pragma unroll
        for (int r = 0; r < 4; ++r) {
            int rl = quad * 4 + r;
            sr[r] = (rl < rows) ? srcp[start + rl] : 0;
        }
        f32x4 acc[6];
#pragma unroll
        for (int t = 0; t < 6; ++t) {
            acc[t] = (f32x4){0.f, 0.f, 0.f, 0.f};
#pragma unroll
            for (int c = 0; c < 3; ++c)
                acc[t] = __builtin_amdgcn_mfma_f32_16x16x32_bf16(a[c], bfrag[t][c], acc[t], 0, 0, 0);
        }
        float nacc[6] = {0.f, 0.f, 0.f, 0.f, 0.f, 0.f};
        float dacc[6] = {0.f, 0.f, 0.f, 0.f, 0.f, 0.f};
#pragma unroll
        for (int r = 0; r < 4; ++r) {
            const int rl = quad * 4 + r;
            if (rl < rows) {
                const long s = sr[r];
                const u16* dp = Dh + s * DD + lm * 6;
                const u16* bp = Bh + s * DD + lm * 6;
                u16* ep = ebuf + (long)(start + rl) * DD + lm * 6;
                u32 d0 = *(const u32*)dp, d1 = *(const u32*)(dp + 2), d2 = *(const u32*)(dp + 4);
                u32 b0 = *(const u32*)bp, b1 = *(const u32*)(bp + 2), b2 = *(const u32*)(bp + 4);
                u32 o0 = *(const u32*)ep, o1 = *(const u32*)(ep + 2), o2 = *(const u32*)(ep + 4);
                float dh[6] = {unlo(d0), unhi(d0), unlo(d1), unhi(d1), unlo(d2), unhi(d2)};
                float bh[6] = {unlo(b0), unhi(b0), unlo(b1), unhi(b1), unlo(b2), unhi(b2)};
                float od[6] = {unlo(o0), unhi(o0), unlo(o1), unhi(o1), unlo(o2), unhi(o2)};
                float ov[6];
#pragma unroll
                for (int t = 0; t < 6; ++t) {
                    float en = acc[t][r] + cb[t] + dh[t] + eh[t];
                    float sg = 1.f / (1.f + __expf(-en));
                    nacc[t] += bh[t] * sg;
                    dacc[t] += sg;
                    ov[t] = od[t] + fmaxf(en, 0.f);
                }
                *(u32*)ep       = pk2(ov[0], ov[1]);
                *(u32*)(ep + 2) = pk2(ov[2], ov[3]);
                *(u32*)(ep + 4) = pk2(ov[4], ov[5]);
            }
        }
#pragma unroll
        for (int t = 0; t < 6; ++t) {
            float x = nacc[t], y = dacc[t];
            x += __shfl_xor(x, 16); y += __shfl_xor(y, 16);
            x += __shfl_xor(x, 32); y += __shfl_xor(y, 32);
            nacc[t] = x; dacc[t] = y;
        }
        if (quad == 0) {
#pragma unroll
            for (int t = 0; t < 6; ++t)
                atomicAdd(&num[(long)n * DD + t * 16 + lm], nacc[t]);
        } else if (quad == 1) {
#pragma unroll
            for (int t = 0; t < 6; ++t)
                atomicAdd(&den[(long)n * DD + t * 16 + lm], dacc[t]);
        }
    }
}

// h += relu(Ah + num/(den+eps)), vectorized (canonical basis)
__global__ void k_comb(const float4* __restrict__ Ah, const float4* __restrict__ num,
                       const float4* __restrict__ den, float4* __restrict__ h, int n4) {
    int i = blockIdx.x * blockDim.x + threadIdx.x;
    if (i >= n4) return;
    float4 a = Ah[i], nm = num[i], dn = den[i], hv = h[i];
    hv.x += fmaxf(a.x + nm.x / (dn.x + EPSF), 0.f);
    hv.y += fmaxf(a.y + nm.y / (dn.y + EPSF), 0.f);
    hv.z += fmaxf(a.z + nm.z / (dn.z + EPSF), 0.f);
    hv.w += fmaxf(a.w + nm.w / (dn.w + EPSF), 0.f);
    h[i] = hv;
}

// small MLP stage, one thread per output element
__global__ void k_mlp(const float* __restrict__ X, const float* __restrict__ W,
                      const float* __restrict__ B, float* __restrict__ Y,
                      int K, int Dout, int act, long total) {
    long idx = (long)blockIdx.x * blockDim.x + threadIdx.x;
    if (idx >= total) return;
    int row = (int)(idx / Dout);
    int j = (int)(idx - (long)row * Dout);
    const float* xr = X + (long)row * K;
    float acc = B[j];
    for (int k = 0; k < K; ++k) acc = fmaf(xr[k], W[k * Dout + j], acc);
    if (act == 1) acc = fmaxf(acc, 0.f);
    else if (act == 2) acc = 1.f / (1.f + __expf(-acc));
    Y[idx] = acc;
}

extern "C" void kernel_launch(void* const* d_in, const int* in_sizes, int n_in,
                              void* d_out, int out_size, void* d_ws, size_t ws_size,
                              hipStream_t stream) {
    const float* h_in = (const float*)d_in[0];
    const float* e_in = (const float*)d_in[1];
    const int* src = (const int*)d_in[2];
    const int* dst = (const int*)d_in[3];
    const float* fp_w = (const float*)d_in[4];
    const float* fp_b = (const float*)d_in[5];
    const float* ep_w = (const float*)d_in[6];
    const float* ep_b = (const float*)d_in[7];
    const float* A_w = (const float*)d_in[8];
    const float* A_b = (const float*)d_in[9];
    const float* B_w = (const float*)d_in[10];
    const float* B_b = (const float*)d_in[11];
    const float* C_w = (const float*)d_in[12];
    const float* C_b = (const float*)d_in[13];
    const float* D_w = (const float*)d_in[14];
    const float* D_b = (const float*)d_in[15];
    const float* E_w = (const float*)d_in[16];
    const float* E_b = (const float*)d_in[17];
    const float* mlp0_w = (const float*)d_in[18];
    const float* mlp0_b = (const float*)d_in[19];
    const float* mlp1_w = (const float*)d_in[20];
    const float* mlp1_b = (const float*)d_in[21];
    const float* mlp2_w = (const float*)d_in[22];
    const float* mlp2_b = (const float*)d_in[23];
    float* out = (float*)d_out;

    const size_t ND = (size_t)NN * DD;
    const size_t ED = (size_t)NE * DD;
    const size_t FRAG = (size_t)NL * 6 * 3 * 64 * 8;
    const int MAXCH = NN + NE / 16 + 64;   // chunk-count upper bound
    char* w = (char*)d_ws;
    float* hbuf = (float*)w; w += ND * 4;
    float* Ahb  = (float*)w; w += ND * 4;
    float* numb = (float*)w; w += ND * 4;   // adjacent -> single zero pass
    float* denb = (float*)w; w += ND * 4;
    u16* Bhb = (u16*)w; w += ND * 2;
    u16* Dhb = (u16*)w; w += ND * 2;
    u16* Ehb = (u16*)w; w += ND * 2;
    u16* ebuf = (u16*)w; w += ED * 2;
    int* counts  = (int*)w; w += (size_t)NN * 4;
    int* row_ptr = (int*)w; w += (size_t)(NN + 1) * 4 + 12;
    int* cursor  = (int*)w; w += (size_t)NN * 4;
    int* eperm   = (int*)w; w += (size_t)NE * 4;
    int* srcp    = (int*)w; w += (size_t)NE * 4;
    int* chunk_ptr  = (int*)w; w += (size_t)(NN + 1) * 4 + 12;
    int* chunk_node = (int*)w; w += (size_t)MAXCH * 4;
    int* chunk_start= (int*)w; w += (size_t)MAXCH * 4;
    u16* awf = (u16*)w; w += FRAG * 2;
    u16* bwf = (u16*)w; w += FRAG * 2;
    u16* cwf = (u16*)w; w += FRAG * 2;
    u16* dwf = (u16*)w; w += FRAG * 2;
    u16* ewf = (u16*)w; w += FRAG * 2;
    u16* wfp = (u16*)w; w += (size_t)6 * 64 * 8 * 2;
    u16* wep = (u16*)w; w += (size_t)6 * 64 * 8 * 2;
    size_t need = (size_t)(w - (char*)d_ws);
    if (ws_size < need) return;  // uniform -> graph-safe; fails absmax as diagnostic

    // CSR build + chunk list + weight fragment packs
    k_zero_i<<<(NN + 255) / 256, 256, 0, stream>>>(counts, NN);
    k_hist<<<(NE + 255) / 256, 256, 0, stream>>>(dst, counts);
    k_scan<<<1, 1024, 0, stream>>>(counts, row_ptr, cursor, NN);
    k_scatter<<<(NE + 255) / 256, 256, 0, stream>>>(src, dst, cursor, eperm, srcp);
    k_chunkcnt<<<(NN + 255) / 256, 256, 0, stream>>>(row_ptr, counts);
    k_scan<<<1, 1024, 0, stream>>>(counts, chunk_ptr, cursor, NN);
    k_fillchunk<<<(NN + 255) / 256, 256, 0, stream>>>(row_ptr, chunk_ptr, chunk_node, chunk_start);
    const int gPack = (NL * 6 * 3 * 64 + 255) / 256;
    k_packCw<<<gPack, 256, 0, stream>>>(A_w, awf, 0);
    k_packCw<<<gPack, 256, 0, stream>>>(B_w, bwf, 0);
    k_packCw<<<gPack, 256, 0, stream>>>(C_w, cwf, 1);   // k-permuted (e-state basis)
    k_packCw<<<gPack, 256, 0, stream>>>(D_w, dwf, 0);
    k_packCw<<<gPack, 256, 0, stream>>>(E_w, ewf, 0);
    k_packW32<<<2, 256, 0, stream>>>(fp_w, wfp);
    k_packW32<<<2, 256, 0, stream>>>(ep_w, wep);

    // input projections (h canonical f32; e bf16 permuted basis, dst-sorted)
    k_proj_m<false, false, false><<<256, 256, 0, stream>>>(h_in, wfp, fp_b, hbuf, nullptr, NN / 16);
    k_proj_m<true, true, true><<<1024, 256, 0, stream>>>(e_in, wep, ep_b, ebuf, eperm, NE / 16);

    const size_t LFRAG = (size_t)6 * 3 * 64 * 8;
    const int zn4 = (int)(2 * ND / 4);
    for (int l = 0; l < NL; ++l) {
        const float* Ab = A_b + (size_t)l * DD;
        const float* Bb = B_b + (size_t)l * DD;
        const float* Cb = C_b + (size_t)l * DD;
        const float* Db = D_b + (size_t)l * DD;
        const float* Eb = E_b + (size_t)l * DD;

        k_gemm4m<<<3125, 256, 0, stream>>>(hbuf,
                                           awf + l * LFRAG, Ab, bwf + l * LFRAG, Bb,
                                           dwf + l * LFRAG, Db, ewf + l * LFRAG, Eb,
                                           Ahb, Bhb, Dhb, Ehb, NN / 16);
        k_zero_f4<<<(zn4 + 255) / 256, 256, 0, stream>>>((float4*)numb, zn4);
        k_edge_c<<<2560, 256, 0, stream>>>(ebuf, cwf + l * LFRAG, Cb, Dhb, Ehb, Bhb,
                                           srcp, row_ptr, chunk_node, chunk_start,
                                           chunk_ptr + NN, numb, denb);
        k_comb<<<(int)((ND / 4 + 255) / 256), 256, 0, stream>>>(
            (const float4*)Ahb, (const float4*)numb, (const float4*)denb, (float4*)hbuf,
            (int)(ND / 4));
    }

    // MLP readout: 96 -> 48 (relu) -> 24 (relu) -> 10 (sigmoid). Reuse Ahb as temps.
    float* y1 = Ahb;
    float* y2 = Ahb + (size_t)NN * 48;
    long t0 = (long)NN * 48, t1 = (long)NN * 24, t2 = (long)NN * NCLS;
    k_mlp<<<(int)((t0 + 255) / 256), 256, 0, stream>>>(hbuf, mlp0_w, mlp0_b, y1, DD, 48, 1, t0);
    k_mlp<<<(int)((t1 + 255) / 256), 256, 0, stream>>>(y1, mlp1_w, mlp1_b, y2, 48, 24, 1, t1);
    k_mlp<<<(int)((t2 + 255) / 256), 256, 0, stream>>>(y2, mlp2_w, mlp2_b, out, 24, NCLS, 2, t2);
}

// Round 14
// 1456.788 us; speedup vs baseline: 1.0631x; 1.0631x over previous
//
#include <hip/hip_runtime.h>

#define NN 50000
#define NE 800000
#define DIN 32
#define DD 96
#define NL 4
#define NCLS 10
#define EPSF 1e-6f

typedef unsigned short u16;
typedef unsigned int u32;

typedef __bf16 bf16x8 __attribute__((ext_vector_type(8)));
typedef float f32x4 __attribute__((ext_vector_type(4)));

static __device__ __forceinline__ float bf2f(u16 u) {
    return __uint_as_float(((u32)u) << 16);
}
static __device__ __forceinline__ u16 f2bf(float f) {
    u32 x = __float_as_uint(f);
    x += 0x7FFFu + ((x >> 16) & 1u);   // round-to-nearest-even
    return (u16)(x >> 16);
}
static __device__ __forceinline__ u32 pk2(float a, float b) {
    return (u32)f2bf(a) | ((u32)f2bf(b) << 16);
}
static __device__ __forceinline__ float unlo(u32 u) { return __uint_as_float(u << 16); }
static __device__ __forceinline__ float unhi(u32 u) { return __uint_as_float(u & 0xFFFF0000u); }

__global__ void k_zero_i(int* __restrict__ p, int n) {
    int i = blockIdx.x * blockDim.x + threadIdx.x;
    if (i < n) p[i] = 0;
}

__global__ void k_hist(const int* __restrict__ dst, int* __restrict__ counts) {
    int i = blockIdx.x * blockDim.x + threadIdx.x;
    if (i < NE) atomicAdd(&counts[dst[i]], 1);
}

// single-block exclusive scan over n counts -> ptr[0..n], cursor copy.
__global__ __launch_bounds__(1024) void k_scan(const int* __restrict__ counts,
                                               int* __restrict__ ptr,
                                               int* __restrict__ cursor, int n) {
    __shared__ int wsum[16];
    __shared__ int carry_s;
    const int tid = threadIdx.x;
    const int lane = tid & 63, wid = tid >> 6;
    if (tid == 0) carry_s = 0;
    __syncthreads();
    for (int base = 0; base < n; base += 1024) {
        int i = base + tid;
        int v = (i < n) ? counts[i] : 0;
        int x = v;
#pragma unroll
        for (int off = 1; off < 64; off <<= 1) {
            int t = __shfl_up(x, (unsigned)off, 64);
            if (lane >= off) x += t;
        }
        if (lane == 63) wsum[wid] = x;
        __syncthreads();
        if (wid == 0 && lane < 16) {
            int s = wsum[lane];
#pragma unroll
            for (int off = 1; off < 16; off <<= 1) {
                int t = __shfl_up(s, (unsigned)off, 16);
                if (lane >= off) s += t;
            }
            wsum[lane] = s;
        }
        __syncthreads();
        int wbase = (wid > 0) ? wsum[wid - 1] : 0;
        int carry = carry_s;
        int excl = carry + wbase + x - v;
        if (i < n) { ptr[i] = excl; cursor[i] = excl; }
        __syncthreads();
        if (tid == 0) carry_s = carry + wsum[15];
        __syncthreads();
    }
    if (tid == 0) ptr[n] = carry_s;
}

__global__ void k_scatter(const int* __restrict__ src, const int* __restrict__ dst,
                          int* __restrict__ cursor, int* __restrict__ eperm,
                          int* __restrict__ srcp) {
    int i = blockIdx.x * blockDim.x + threadIdx.x;
    if (i >= NE) return;
    int pos = atomicAdd(&cursor[dst[i]], 1);
    eperm[pos] = i;
    srcp[pos] = src[i];
}

// Pack a [NL][96][96] weight tensor into MFMA B-fragment order (bf16).
// kperm!=0: k-axis permuted by pi(k)=(k%6)*16+k/6 (Cw: e-state stored-pi k).
__global__ void k_packCw(const float* __restrict__ W_all, u16* __restrict__ wf, int kperm) {
    int q = blockIdx.x * blockDim.x + threadIdx.x;
    if (q >= NL * 6 * 3 * 64) return;
    int l = q / (6 * 3 * 64);
    int rem = q - l * (6 * 3 * 64);
    int tile = rem / (3 * 64);
    int rem2 = rem - tile * (3 * 64);
    int c = rem2 >> 6, lane = rem2 & 63;
    const float* W = W_all + (long)l * DD * DD;
    int n = tile * 16 + (lane & 15);
    int k0 = c * 32 + (lane >> 4) * 8;
    u16 w[8];
#pragma unroll
    for (int j = 0; j < 8; ++j) {
        int kk = k0 + j;
        int kact = kperm ? ((kk % 6) * 16 + kk / 6) : kk;
        w[j] = f2bf(W[kact * DD + n]);
    }
    *(uint4*)&wf[(long)q * 8] = *(uint4*)w;
}

// Pack a [32,96] projection W into B-fragment order
__global__ void k_packW32(const float* __restrict__ W, u16* __restrict__ wf) {
    int q = blockIdx.x * blockDim.x + threadIdx.x;
    if (q >= 6 * 64) return;
    int tile = q >> 6, lane = q & 63;
    int n = tile * 16 + (lane & 15);
    int k0 = (lane >> 4) * 8;
    u16 w[8];
#pragma unroll
    for (int j = 0; j < 8; ++j) w[j] = f2bf(W[(k0 + j) * DD + n]);
    *(uint4*)&wf[q * 8] = *(uint4*)w;
}

// Barrier-free MFMA input projection: one wave per 16-row tile, grid-stride.
template <bool BFOUT, bool PERM, bool POUT>
__global__ __launch_bounds__(256) void k_proj_m(const float* __restrict__ X,
                                                const u16* __restrict__ wf,
                                                const float* __restrict__ B,
                                                void* __restrict__ Y,
                                                const int* __restrict__ eperm,
                                                int ntiles) {
    const int lane = threadIdx.x & 63;
    const int gw = (blockIdx.x * blockDim.x + threadIdx.x) >> 6;
    const int nw = (gridDim.x * blockDim.x) >> 6;
    const int lm = lane & 15, quad = lane >> 4;

    bf16x8 bfr[6];
    float bias[6];
#pragma unroll
    for (int t = 0; t < 6; ++t) {
        bfr[t] = *(const bf16x8*)&wf[(t * 64 + lane) * 8];
        bias[t] = B[t * 16 + lm];
    }

    for (int tile = gw; tile < ntiles; tile += nw) {
        const int row = tile * 16 + lm;
        const long srow = PERM ? (long)eperm[row] : (long)row;
        float4 x0 = *(const float4*)&X[srow * DIN + quad * 8];
        float4 x1 = *(const float4*)&X[srow * DIN + quad * 8 + 4];
        u32 ap[4] = {pk2(x0.x, x0.y), pk2(x0.z, x0.w), pk2(x1.x, x1.y), pk2(x1.z, x1.w)};
        bf16x8 af = *(bf16x8*)ap;
        f32x4 acc[6];
#pragma unroll
        for (int t = 0; t < 6; ++t) {
            acc[t] = (f32x4){0.f, 0.f, 0.f, 0.f};
            acc[t] = __builtin_amdgcn_mfma_f32_16x16x32_bf16(af, bfr[t], acc[t], 0, 0, 0);
        }
        const long rbase = (long)tile * 16 + quad * 4;
        if (POUT) {
#pragma unroll
            for (int r = 0; r < 4; ++r) {
                u16* p = (u16*)Y + (rbase + r) * DD + lm * 6;
                *(u32*)p       = pk2(acc[0][r] + bias[0], acc[1][r] + bias[1]);
                *(u32*)(p + 2) = pk2(acc[2][r] + bias[2], acc[3][r] + bias[3]);
                *(u32*)(p + 4) = pk2(acc[4][r] + bias[4], acc[5][r] + bias[5]);
            }
        } else {
#pragma unroll
            for (int t = 0; t < 6; ++t) {
                const int j = t * 16 + lm;
#pragma unroll
                for (int r = 0; r < 4; ++r) {
                    float v = acc[t][r] + bias[t];
                    if (BFOUT) ((u16*)Y)[(rbase + r) * DD + j] = f2bf(v);
                    else       ((float*)Y)[(rbase + r) * DD + j] = v;
                }
            }
        }
    }
}

// Barrier-free MFMA 4-way node GEMM: wave w of each block handles matrix w.
__global__ __launch_bounds__(256) void k_gemm4m(const float* __restrict__ X,
                                                const u16* __restrict__ awf, const float* __restrict__ ab,
                                                const u16* __restrict__ bwf, const float* __restrict__ bb,
                                                const u16* __restrict__ dwf, const float* __restrict__ db,
                                                const u16* __restrict__ ewf, const float* __restrict__ eb,
                                                float* __restrict__ Y0, u16* __restrict__ Y1,
                                                u16* __restrict__ Y2, u16* __restrict__ Y3,
                                                int ntiles) {
    const int lane = threadIdx.x & 63;
    const int w = threadIdx.x >> 6;   // matrix 0..3
    const int lm = lane & 15, quad = lane >> 4;
    const u16* wf = (w == 0) ? awf : (w == 1) ? bwf : (w == 2) ? dwf : ewf;
    const float* bp = (w == 0) ? ab : (w == 1) ? bb : (w == 2) ? db : eb;

    bf16x8 bfr[6][3];
    float bias[6];
#pragma unroll
    for (int t = 0; t < 6; ++t) {
#pragma unroll
        for (int c = 0; c < 3; ++c)
            bfr[t][c] = *(const bf16x8*)&wf[((t * 3 + c) * 64 + lane) * 8];
        bias[t] = bp[t * 16 + lm];
    }

    for (int tile = blockIdx.x; tile < ntiles; tile += gridDim.x) {
        const float* xr = X + (long)(tile * 16 + lm) * DD;
        bf16x8 a[3];
#pragma unroll
        for (int c = 0; c < 3; ++c) {
            float4 x0 = *(const float4*)&xr[c * 32 + quad * 8];
            float4 x1 = *(const float4*)&xr[c * 32 + quad * 8 + 4];
            u32 ap[4] = {pk2(x0.x, x0.y), pk2(x0.z, x0.w), pk2(x1.x, x1.y), pk2(x1.z, x1.w)};
            a[c] = *(bf16x8*)ap;
        }
        f32x4 acc[6];
#pragma unroll
        for (int t = 0; t < 6; ++t) {
            acc[t] = (f32x4){0.f, 0.f, 0.f, 0.f};
#pragma unroll
            for (int c = 0; c < 3; ++c)
                acc[t] = __builtin_amdgcn_mfma_f32_16x16x32_bf16(a[c], bfr[t][c], acc[t], 0, 0, 0);
        }
        const long rbase = (long)tile * 16 + quad * 4;
        if (w == 0) {
#pragma unroll
            for (int t = 0; t < 6; ++t) {
                const int j = t * 16 + lm;
#pragma unroll
                for (int r = 0; r < 4; ++r) Y0[(rbase + r) * DD + j] = acc[t][r] + bias[t];
            }
        } else {
            u16* Yp = (w == 1) ? Y1 : (w == 2) ? Y2 : Y3;
#pragma unroll
            for (int r = 0; r < 4; ++r) {
                u16* p = Yp + (rbase + r) * DD + lm * 6;
                *(u32*)p       = pk2(acc[0][r] + bias[0], acc[1][r] + bias[1]);
                *(u32*)(p + 2) = pk2(acc[2][r] + bias[2], acc[3][r] + bias[3]);
                *(u32*)(p + 4) = pk2(acc[4][r] + bias[4], acc[5][r] + bias[5]);
            }
        }
    }
}

// LDS-free... rather: register-lean fused edge+aggregate, one wave per node.
// Cw B-fragments live in LDS (18 KB/block, staged once) instead of 72 VGPRs,
// lifting waves/SIMD from 4 to ~6. Epilogue in permuted basis (3x u32/row).
__global__ __launch_bounds__(256) void k_node_edge_w(u16* ebuf,
                                                     const u16* __restrict__ cwf,
                                                     const float* __restrict__ Cb,
                                                     const u16* __restrict__ Dh,
                                                     const u16* __restrict__ Eh,
                                                     const u16* __restrict__ Bh,
                                                     const int* __restrict__ srcp,
                                                     const int* __restrict__ row_ptr,
                                                     const float* __restrict__ Ah,
                                                     float* __restrict__ hbuf) {
    __shared__ u16 cwlds[18 * 64 * 8];   // 18 KB: [t*3+c][lane][8]
    const int tid = threadIdx.x;
    const int lane = tid & 63;
    const int gw = (blockIdx.x * blockDim.x + tid) >> 6;
    const int nw = (gridDim.x * blockDim.x) >> 6;
    const int lm = lane & 15, quad = lane >> 4;

    // stage Cw fragments into LDS (coalesced uint4 copies)
#pragma unroll
    for (int q = tid; q < 18 * 64 * 8 / 8; q += 256)
        *(uint4*)&cwlds[q * 8] = *(const uint4*)&cwf[q * 8];
    float cb[6];
#pragma unroll
    for (int t = 0; t < 6; ++t) cb[t] = Cb[t * 16 + lm];
    __syncthreads();

    for (int n = gw; n < NN; n += nw) {
        const int r0 = row_ptr[n], r1 = row_ptr[n + 1];
        float eh[6];
        {
            const u16* ep = Eh + (long)n * DD + lm * 6;
            u32 e0 = *(const u32*)ep, e1 = *(const u32*)(ep + 2), e2 = *(const u32*)(ep + 4);
            eh[0] = unlo(e0); eh[1] = unhi(e0); eh[2] = unlo(e1);
            eh[3] = unhi(e1); eh[4] = unlo(e2); eh[5] = unhi(e2);
        }
        float nacc[6] = {0.f, 0.f, 0.f, 0.f, 0.f, 0.f};
        float dacc[6] = {0.f, 0.f, 0.f, 0.f, 0.f, 0.f};

        for (int chunk = r0; chunk < r1; chunk += 16) {
            const int rows = r1 - chunk < 16 ? r1 - chunk : 16;
            const long arow = chunk + (lm < rows ? lm : 0);
            bf16x8 a[3];
#pragma unroll
            for (int c = 0; c < 3; ++c)
                a[c] = *(const bf16x8*)&ebuf[arow * DD + c * 32 + quad * 8];
            int sr[4];
#pragma unroll
            for (int r = 0; r < 4; ++r) {
                int rl = quad * 4 + r;
                sr[r] = (chunk + rl < r1) ? srcp[chunk + rl] : 0;
            }
            f32x4 acc[6];
#pragma unroll
            for (int t = 0; t < 6; ++t) {
                acc[t] = (f32x4){0.f, 0.f, 0.f, 0.f};
#pragma unroll
                for (int c = 0; c < 3; ++c) {
                    bf16x8 b = *(const bf16x8*)&cwlds[((t * 3 + c) * 64 + lane) * 8];
                    acc[t] = __builtin_amdgcn_mfma_f32_16x16x32_bf16(a[c], b, acc[t], 0, 0, 0);
                }
            }
            // epilogue: row = quad*4+r; lane owns stored cols lm*6..lm*6+5
#pragma unroll
            for (int r = 0; r < 4; ++r) {
                const int rl = quad * 4 + r;
                if (rl < rows) {
                    const long s = sr[r];
                    const u16* dp = Dh + s * DD + lm * 6;
                    const u16* bp = Bh + s * DD + lm * 6;
                    u16* ep = ebuf + (long)(chunk + rl) * DD + lm * 6;
                    u32 d0 = *(const u32*)dp, d1 = *(const u32*)(dp + 2), d2 = *(const u32*)(dp + 4);
                    u32 b0 = *(const u32*)bp, b1 = *(const u32*)(bp + 2), b2 = *(const u32*)(bp + 4);
                    u32 o0 = *(const u32*)ep, o1 = *(const u32*)(ep + 2), o2 = *(const u32*)(ep + 4);
                    float dh[6] = {unlo(d0), unhi(d0), unlo(d1), unhi(d1), unlo(d2), unhi(d2)};
                    float bh[6] = {unlo(b0), unhi(b0), unlo(b1), unhi(b1), unlo(b2), unhi(b2)};
                    float od[6] = {unlo(o0), unhi(o0), unlo(o1), unhi(o1), unlo(o2), unhi(o2)};
                    float ov[6];
#pragma unroll
                    for (int t = 0; t < 6; ++t) {
                        float en = acc[t][r] + cb[t] + dh[t] + eh[t];
                        float sg = 1.f / (1.f + __expf(-en));
                        nacc[t] += bh[t] * sg;
                        dacc[t] += sg;
                        ov[t] = od[t] + fmaxf(en, 0.f);
                    }
                    *(u32*)ep       = pk2(ov[0], ov[1]);
                    *(u32*)(ep + 2) = pk2(ov[2], ov[3]);
                    *(u32*)(ep + 4) = pk2(ov[4], ov[5]);
                }
            }
        }
        // reduce over quads (butterfly across lane bits 4-5)
#pragma unroll
        for (int t = 0; t < 6; ++t) {
            float x = nacc[t], y = dacc[t];
            x += __shfl_xor(x, 16); y += __shfl_xor(y, 16);
            x += __shfl_xor(x, 32); y += __shfl_xor(y, 32);
            nacc[t] = x; dacc[t] = y;
        }
        if (quad == 0) {
#pragma unroll
            for (int t = 0; t < 6; ++t) {
                const int j = t * 16 + lm;   // actual col of stored p=lm*6+t
                float val = Ah[(long)n * DD + j] + nacc[t] / (dacc[t] + EPSF);
                hbuf[(long)n * DD + j] += fmaxf(val, 0.f);
            }
        }
    }
}

// small MLP stage, one thread per output element
__global__ void k_mlp(const float* __restrict__ X, const float* __restrict__ W,
                      const float* __restrict__ B, float* __restrict__ Y,
                      int K, int Dout, int act, long total) {
    long idx = (long)blockIdx.x * blockDim.x + threadIdx.x;
    if (idx >= total) return;
    int row = (int)(idx / Dout);
    int j = (int)(idx - (long)row * Dout);
    const float* xr = X + (long)row * K;
    float acc = B[j];
    for (int k = 0; k < K; ++k) acc = fmaf(xr[k], W[k * Dout + j], acc);
    if (act == 1) acc = fmaxf(acc, 0.f);
    else if (act == 2) acc = 1.f / (1.f + __expf(-acc));
    Y[idx] = acc;
}

extern "C" void kernel_launch(void* const* d_in, const int* in_sizes, int n_in,
                              void* d_out, int out_size, void* d_ws, size_t ws_size,
                              hipStream_t stream) {
    const float* h_in = (const float*)d_in[0];
    const float* e_in = (const float*)d_in[1];
    const int* src = (const int*)d_in[2];
    const int* dst = (const int*)d_in[3];
    const float* fp_w = (const float*)d_in[4];
    const float* fp_b = (const float*)d_in[5];
    const float* ep_w = (const float*)d_in[6];
    const float* ep_b = (const float*)d_in[7];
    const float* A_w = (const float*)d_in[8];
    const float* A_b = (const float*)d_in[9];
    const float* B_w = (const float*)d_in[10];
    const float* B_b = (const float*)d_in[11];
    const float* C_w = (const float*)d_in[12];
    const float* C_b = (const float*)d_in[13];
    const float* D_w = (const float*)d_in[14];
    const float* D_b = (const float*)d_in[15];
    const float* E_w = (const float*)d_in[16];
    const float* E_b = (const float*)d_in[17];
    const float* mlp0_w = (const float*)d_in[18];
    const float* mlp0_b = (const float*)d_in[19];
    const float* mlp1_w = (const float*)d_in[20];
    const float* mlp1_b = (const float*)d_in[21];
    const float* mlp2_w = (const float*)d_in[22];
    const float* mlp2_b = (const float*)d_in[23];
    float* out = (float*)d_out;

    const size_t ND = (size_t)NN * DD;
    const size_t ED = (size_t)NE * DD;
    const size_t FRAG = (size_t)NL * 6 * 3 * 64 * 8;
    char* w = (char*)d_ws;
    float* hbuf = (float*)w; w += ND * 4;
    float* Ahb  = (float*)w; w += ND * 4;
    u16* Bhb = (u16*)w; w += ND * 2;
    u16* Dhb = (u16*)w; w += ND * 2;
    u16* Ehb = (u16*)w; w += ND * 2;
    u16* ebuf = (u16*)w; w += ED * 2;
    int* counts  = (int*)w; w += (size_t)NN * 4;
    int* row_ptr = (int*)w; w += (size_t)(NN + 1) * 4 + 12;
    int* cursor  = (int*)w; w += (size_t)NN * 4;
    int* eperm   = (int*)w; w += (size_t)NE * 4;
    int* srcp    = (int*)w; w += (size_t)NE * 4;
    u16* awf = (u16*)w; w += FRAG * 2;
    u16* bwf = (u16*)w; w += FRAG * 2;
    u16* cwf = (u16*)w; w += FRAG * 2;
    u16* dwf = (u16*)w; w += FRAG * 2;
    u16* ewf = (u16*)w; w += FRAG * 2;
    u16* wfp = (u16*)w; w += (size_t)6 * 64 * 8 * 2;
    u16* wep = (u16*)w; w += (size_t)6 * 64 * 8 * 2;
    size_t need = (size_t)(w - (char*)d_ws);
    if (ws_size < need) return;  // uniform -> graph-safe; fails absmax as diagnostic

    // CSR build (dst-sorted edge permutation) + weight fragment packs
    k_zero_i<<<(NN + 255) / 256, 256, 0, stream>>>(counts, NN);
    k_hist<<<(NE + 255) / 256, 256, 0, stream>>>(dst, counts);
    k_scan<<<1, 1024, 0, stream>>>(counts, row_ptr, cursor, NN);
    k_scatter<<<(NE + 255) / 256, 256, 0, stream>>>(src, dst, cursor, eperm, srcp);
    const int gPack = (NL * 6 * 3 * 64 + 255) / 256;
    k_packCw<<<gPack, 256, 0, stream>>>(A_w, awf, 0);
    k_packCw<<<gPack, 256, 0, stream>>>(B_w, bwf, 0);
    k_packCw<<<gPack, 256, 0, stream>>>(C_w, cwf, 1);   // k-permuted (e-state basis)
    k_packCw<<<gPack, 256, 0, stream>>>(D_w, dwf, 0);
    k_packCw<<<gPack, 256, 0, stream>>>(E_w, ewf, 0);
    k_packW32<<<2, 256, 0, stream>>>(fp_w, wfp);
    k_packW32<<<2, 256, 0, stream>>>(ep_w, wep);

    // input projections (h canonical f32; e bf16 permuted basis, dst-sorted)
    k_proj_m<false, false, false><<<256, 256, 0, stream>>>(h_in, wfp, fp_b, hbuf, nullptr, NN / 16);
    k_proj_m<true, true, true><<<1024, 256, 0, stream>>>(e_in, wep, ep_b, ebuf, eperm, NE / 16);

    const size_t LFRAG = (size_t)6 * 3 * 64 * 8;
    for (int l = 0; l < NL; ++l) {
        const float* Ab = A_b + (size_t)l * DD;
        const float* Bb = B_b + (size_t)l * DD;
        const float* Cb = C_b + (size_t)l * DD;
        const float* Db = D_b + (size_t)l * DD;
        const float* Eb = E_b + (size_t)l * DD;

        k_gemm4m<<<3125, 256, 0, stream>>>(hbuf,
                                           awf + l * LFRAG, Ab, bwf + l * LFRAG, Bb,
                                           dwf + l * LFRAG, Db, ewf + l * LFRAG, Eb,
                                           Ahb, Bhb, Dhb, Ehb, NN / 16);
        k_node_edge_w<<<2560, 256, 0, stream>>>(ebuf, cwf + l * LFRAG, Cb, Dhb, Ehb, Bhb,
                                                srcp, row_ptr, Ahb, hbuf);
    }

    // MLP readout: 96 -> 48 (relu) -> 24 (relu) -> 10 (sigmoid). Reuse Ahb as temps.
    float* y1 = Ahb;
    float* y2 = Ahb + (size_t)NN * 48;
    long t0 = (long)NN * 48, t1 = (long)NN * 24, t2 = (long)NN * NCLS;
    k_mlp<<<(int)((t0 + 255) / 256), 256, 0, stream>>>(hbuf, mlp0_w, mlp0_b, y1, DD, 48, 1, t0);
    k_mlp<<<(int)((t1 + 255) / 256), 256, 0, stream>>>(y1, mlp1_w, mlp1_b, y2, 48, 24, 1, t1);
    k_mlp<<<(int)((t2 + 255) / 256), 256, 0, stream>>>(y2, mlp2_w, mlp2_b, out, 24, NCLS, 2, t2);
}